// Round 1
// baseline (132.849 us; speedup 1.0000x reference)
//
#include <hip/hip_runtime.h>

#define NATOMS 2048
#define A_DIM 64
#define R_DIM 512
#define P_DIM 256
#define S_DIM 4
#define NSTACKS 32
#define F_DIM 8192
#define KS 4            // K splits
#define KSPAN (R_DIM / KS)  // 128
#define TR 128          // rows per tile
#define TC 64           // cols per tile
#define KT 16           // k chunk

// ws layout:
//   [0, 8192)        : order  (int[2048])
//   [8192, 8224)     : meta   (gstart[4], gcount[4])
//   [16384, +8MB)    : proj partials  float[KS][2048][256]

__global__ __launch_bounds__(256) void sorf_sort_kernel(
    const int* __restrict__ charges, int* __restrict__ order, int* __restrict__ meta) {
  __shared__ int cnt[S_DIM];
  __shared__ int base[S_DIM];
  int t = threadIdx.x;
  if (t < S_DIM) cnt[t] = 0;
  __syncthreads();
  for (int i = t; i < NATOMS; i += 256) atomicAdd(&cnt[charges[i]], 1);
  __syncthreads();
  if (t == 0) {
    int run = 0;
    for (int s = 0; s < S_DIM; ++s) {
      base[s] = run; meta[s] = run; meta[4 + s] = cnt[s]; run += cnt[s];
    }
  }
  __syncthreads();
  for (int i = t; i < NATOMS; i += 256) {
    int s = charges[i];
    int pos = atomicAdd(&base[s], 1);
    order[pos] = i;
  }
}

__global__ __launch_bounds__(128) void sorf_proj_kernel(
    const float* __restrict__ rep, const float* __restrict__ reductors,
    const int* __restrict__ order, const int* __restrict__ meta,
    float* __restrict__ projp) {
  int bid = blockIdx.x;
  int ks = bid & 3;
  int cb = (bid >> 2) & 3;
  int rb = (bid >> 4) & 15;
  int s  = bid >> 8;
  int cnt = meta[4 + s];
  if (rb * TR >= cnt) return;
  int start = meta[s] + rb * TR;
  int nrows = min(TR, cnt - rb * TR);

  __shared__ int rows[TR];
  __shared__ float As[KT][TR + 4];  // stride 132: pads bank conflicts, keeps 16B align
  __shared__ float Bs[KT][TC];

  int t = threadIdx.x;
  rows[t] = order[start + min(t, nrows - 1)];
  __syncthreads();

  int tx = t & 7;        // col group -> 8 cols
  int ty = t >> 3;       // row group -> 8 rows
  int c0 = tx * 8;
  int r0 = ty * 8;

  float acc[8][8];
#pragma unroll
  for (int i = 0; i < 8; ++i)
#pragma unroll
    for (int j = 0; j < 8; ++j) acc[i][j] = 0.f;

  const float* repRow = rep + (size_t)rows[t] * R_DIM + ks * KSPAN;
  const float* Bsrc = reductors + ((size_t)s * R_DIM + ks * KSPAN) * P_DIM + cb * TC;
  int kb = t >> 4;
  int cc = (t & 15) * 4;

  for (int k0 = 0; k0 < KSPAN; k0 += KT) {
    float4 a0 = *(const float4*)(repRow + k0);
    float4 a1 = *(const float4*)(repRow + k0 + 4);
    float4 a2 = *(const float4*)(repRow + k0 + 8);
    float4 a3 = *(const float4*)(repRow + k0 + 12);
    float4 b0 = *(const float4*)(Bsrc + (size_t)(k0 + kb) * P_DIM + cc);
    float4 b1 = *(const float4*)(Bsrc + (size_t)(k0 + kb + 8) * P_DIM + cc);
    __syncthreads();  // previous iteration's reads complete
    float av16[16] = {a0.x, a0.y, a0.z, a0.w, a1.x, a1.y, a1.z, a1.w,
                      a2.x, a2.y, a2.z, a2.w, a3.x, a3.y, a3.z, a3.w};
#pragma unroll
    for (int kk = 0; kk < KT; ++kk) As[kk][t] = av16[kk];
    *(float4*)&Bs[kb][cc] = b0;
    *(float4*)&Bs[kb + 8][cc] = b1;
    __syncthreads();
#pragma unroll
    for (int kk = 0; kk < KT; ++kk) {
      float4 aA = *(const float4*)&As[kk][r0];
      float4 aB = *(const float4*)&As[kk][r0 + 4];
      float4 bA = *(const float4*)&Bs[kk][c0];
      float4 bB = *(const float4*)&Bs[kk][c0 + 4];
      float av[8] = {aA.x, aA.y, aA.z, aA.w, aB.x, aB.y, aB.z, aB.w};
      float bv[8] = {bA.x, bA.y, bA.z, bA.w, bB.x, bB.y, bB.z, bB.w};
#pragma unroll
      for (int i = 0; i < 8; ++i)
#pragma unroll
        for (int j = 0; j < 8; ++j) acc[i][j] = fmaf(av[i], bv[j], acc[i][j]);
    }
  }

#pragma unroll
  for (int i = 0; i < 8; ++i) {
    int r = r0 + i;
    if (r < nrows) {
      int arow = rows[r];
      float* dst = projp + ((size_t)ks * NATOMS + arow) * P_DIM + cb * TC + c0;
      *(float4*)dst = make_float4(acc[i][0], acc[i][1], acc[i][2], acc[i][3]);
      *(float4*)(dst + 4) = make_float4(acc[i][4], acc[i][5], acc[i][6], acc[i][7]);
    }
  }
}

__global__ __launch_bounds__(256) void sorf_feat_kernel(
    const float* __restrict__ projp, const int* __restrict__ charges,
    const float* __restrict__ Dmat, const float* __restrict__ bias,
    const float* __restrict__ alpha, float* __restrict__ out) {
  const int atom = blockIdx.x;
  const int t = threadIdx.x;
  const int lane = t & 63;
  const int wave = t >> 6;
  const int s = charges[atom];

  // lane holds elements p = 4*lane + k, k=0..3
  float4 p = *((const float4*)(projp + (size_t)atom * P_DIM) + lane);
#pragma unroll
  for (int ks = 1; ks < KS; ++ks) {
    float4 q = *((const float4*)(projp + ((size_t)ks * NATOMS + atom) * P_DIM) + lane);
    p.x += q.x; p.y += q.y; p.z += q.z; p.w += q.w;
  }

  const float* Db = Dmat + (size_t)s * (NSTACKS * P_DIM);
  const float* bb = bias + (size_t)s * F_DIM;
  float accum = 0.f;

  for (int j = wave * 8; j < wave * 8 + 8; ++j) {
    float4 d  = *((const float4*)(Db + j * P_DIM) + lane);
    float4 bi = *((const float4*)(bb + j * P_DIM) + lane);
    float4 al = *((const float4*)(alpha + j * P_DIM) + lane);
    float x0 = (d.x >= 0.f) ? p.x : -p.x;
    float x1 = (d.y >= 0.f) ? p.y : -p.y;
    float x2 = (d.z >= 0.f) ? p.z : -p.z;
    float x3 = (d.w >= 0.f) ? p.w : -p.w;
    // FWHT bits 0,1 in-register
    float t0 = x0 + x1, t1 = x0 - x1, t2 = x2 + x3, t3 = x2 - x3;
    x0 = t0 + t2; x2 = t0 - t2; x1 = t1 + t3; x3 = t1 - t3;
    // FWHT bits 2..7 via cross-lane butterflies (stages commute)
#pragma unroll
    for (int hl = 1; hl <= 32; hl <<= 1) {
      float sg = (lane & hl) ? -1.f : 1.f;
      float y0 = __shfl_xor(x0, hl);
      float y1 = __shfl_xor(x1, hl);
      float y2 = __shfl_xor(x2, hl);
      float y3 = __shfl_xor(x3, hl);
      x0 = fmaf(sg, x0, y0);
      x1 = fmaf(sg, x1, y1);
      x2 = fmaf(sg, x2, y2);
      x3 = fmaf(sg, x3, y3);
    }
    // scale 1/16 (fwht norm), COEFF_NORM = 1.0 exactly
    accum += __cosf(fmaf(x0, 0.0625f, bi.x)) * al.x;
    accum += __cosf(fmaf(x1, 0.0625f, bi.y)) * al.y;
    accum += __cosf(fmaf(x2, 0.0625f, bi.z)) * al.z;
    accum += __cosf(fmaf(x3, 0.0625f, bi.w)) * al.w;
  }

#pragma unroll
  for (int off = 1; off < 64; off <<= 1) accum += __shfl_xor(accum, off);
  __shared__ float wsum[4];
  if (lane == 0) wsum[wave] = accum;
  __syncthreads();
  if (t == 0) {
    // FEAT_NORM = sqrt(2/8192) = 1/64 exactly
    atomicAdd(out + (atom >> 6), 0.015625f * ((wsum[0] + wsum[1]) + (wsum[2] + wsum[3])));
  }
}

extern "C" void kernel_launch(void* const* d_in, const int* in_sizes, int n_in,
                              void* d_out, int out_size, void* d_ws, size_t ws_size,
                              hipStream_t stream) {
  const float* rep       = (const float*)d_in[0];
  const int*   charges   = (const int*)d_in[1];
  const float* reductors = (const float*)d_in[2];
  const float* Dmat      = (const float*)d_in[3];
  const float* bias      = (const float*)d_in[4];
  const float* alpha     = (const float*)d_in[5];
  float* out = (float*)d_out;

  char* ws = (char*)d_ws;
  int*   order = (int*)ws;
  int*   meta  = (int*)(ws + 8192);
  float* projp = (float*)(ws + 16384);

  hipMemsetAsync(d_out, 0, 32 * sizeof(float), stream);
  sorf_sort_kernel<<<1, 256, 0, stream>>>(charges, order, meta);
  sorf_proj_kernel<<<1024, 128, 0, stream>>>(rep, reductors, order, meta, projp);
  sorf_feat_kernel<<<NATOMS, 256, 0, stream>>>(projp, charges, Dmat, bias, alpha, out);
}